// Round 14
// baseline (216.435 us; speedup 1.0000x reference)
//
#include <hip/hip_runtime.h>

#define B_   16
#define C_   128
#define HW_  16384

typedef __attribute__((ext_vector_type(4))) float  floatx4;
typedef __attribute__((ext_vector_type(8))) short  short8;
typedef __attribute__((ext_vector_type(4))) short  short4v;

static __device__ __forceinline__ unsigned short f2bf(float f){
  unsigned int u = __float_as_uint(f);
  u += 0x7FFFu + ((u >> 16) & 1u);
  return (unsigned short)(u >> 16);
}
static __device__ __forceinline__ float bf2f(unsigned short h){
  return __uint_as_float(((unsigned int)h) << 16);
}
static __device__ __forceinline__ float elu1(float v){
  return v > 0.f ? v + 1.f : __expf(v);
}
// xT swizzle key (period 128 in n, so 128-row half-tiles keep the same key)
static __device__ __forceinline__ int keyx(int n){ return ((n >> 1) & 7) ^ ((n >> 4) & 7); }

// ---- K1: x -> xT (bf16, tile-major [b][tile256][n][c] pre-swizzled LDS image) + GN1 partial stats ----
__global__ __launch_bounds__(512) void k_xprep(const float* __restrict__ x,
    unsigned short* __restrict__ xT, float* __restrict__ gn1part){
  int blk = blockIdx.x;                        // b*64 + tile
  int b = blk >> 6, tile = blk & 63;
  int n0 = tile * 256;
  __shared__ unsigned short XS[32768];
  int t = threadIdx.x, w = t >> 6, l = t & 63;
  float sk[4], sk2[4];
  #pragma unroll
  for (int k = 0; k < 4; ++k){ sk[k] = 0.f; sk2[k] = 0.f; }
  #pragma unroll
  for (int k = 0; k < 4; ++k){
    float4 f4[4];
    #pragma unroll
    for (int j = 0; j < 4; ++j){
      int c = 16*w + 4*k + j;
      f4[j] = *(const float4*)(x + ((size_t)(b*128 + c))*HW_ + n0 + 4*l);
    }
    #pragma unroll
    for (int j = 0; j < 4; ++j){
      sk[k]  += f4[j].x + f4[j].y + f4[j].z + f4[j].w;
      sk2[k] += f4[j].x*f4[j].x + f4[j].y*f4[j].y + f4[j].z*f4[j].z + f4[j].w*f4[j].w;
    }
    int c0 = 16*w + 4*k, cs = c0 >> 3, co = c0 & 7;
    #pragma unroll
    for (int i = 0; i < 4; ++i){
      int n = 4*l + i;
      short4v p;
      #pragma unroll
      for (int j = 0; j < 4; ++j) p[j] = (short)f2bf(((const float*)&f4[j])[i]);
      *(short4v*)(XS + n*128 + (((cs ^ keyx(n)) << 3) + co)) = p;
    }
  }
  #pragma unroll
  for (int k = 0; k < 4; ++k){
    float a = sk[k], q = sk2[k];
    #pragma unroll
    for (int o = 32; o; o >>= 1){ a += __shfl_down(a, o); q += __shfl_down(q, o); }
    if (l == 0){
      gn1part[((size_t)blk)*64 + (4*w + k)*2 + 0] = a;
      gn1part[((size_t)blk)*64 + (4*w + k)*2 + 1] = q;
    }
  }
  __syncthreads();
  unsigned short* dst = xT + ((size_t)blk)*32768;
  for (int it = 0; it < 8; ++it){
    int slot = t + it*512;
    *(short8*)(dst + slot*8) = *(const short8*)(XS + slot*8);
  }
}

// ---- K1f: finalize GN1 stats ----
__global__ __launch_bounds__(64) void k_gn1fin(const float* __restrict__ gn1part,
    float* __restrict__ mean, float* __restrict__ rstd){
  int bg = blockIdx.x;
  int b = bg >> 5, g = bg & 31, l = threadIdx.x;
  const float* p = gn1part + ((size_t)(b*64 + l))*64 + g*2;
  float s = p[0], s2 = p[1];
  #pragma unroll
  for (int o = 32; o; o >>= 1){ s += __shfl_down(s, o); s2 += __shfl_down(s2, o); }
  if (l == 0){
    float m = s * (1.f/65536.f);
    float var = s2 * (1.f/65536.f) - m*m;
    mean[bg] = m; rstd[bg] = rsqrtf(var + 1e-5f);
  }
}

// ---- K2: fold GN1 into qkv weights (per batch), w_out -> bf16 ----
__global__ __launch_bounds__(64) void k_fold(const float* __restrict__ wqkv, const float* __restrict__ wout,
    const float* __restrict__ g1w, const float* __restrict__ g1b,
    const float* __restrict__ mean, const float* __restrict__ rstd,
    unsigned short* __restrict__ wqp, float* __restrict__ bias, unsigned short* __restrict__ woutb){
  int i = blockIdx.x, l = threadIdx.x;
  if (i < 6144){
    int b = i / 384, o = i % 384;
    float bsum = 0.f;
    #pragma unroll
    for (int j = 0; j < 2; ++j){
      int c = l*2 + j, g = c >> 2;
      float m = mean[b*32 + g], r = rstd[b*32 + g];
      float A  = r * g1w[c];
      float Bc = g1b[c] - m * A;
      float wv = wqkv[o*128 + c];
      wqp[((size_t)(b*384 + o))*128 + c] = f2bf(wv * A);
      bsum += wv * Bc;
    }
    #pragma unroll
    for (int o2 = 32; o2; o2 >>= 1) bsum += __shfl_down(bsum, o2);
    if (l == 0) bias[b*384 + o] = bsum;
  } else {
    int r = i - 6144;
    #pragma unroll
    for (int j = 0; j < 2; ++j){ int c = l*2 + j; woutb[r*128 + c] = f2bf(wout[r*128 + c]); }
  }
}

// ---- K3: k,v GEMM (operand-swapped -> n-major D, b64 image writes), one 128-n tile per block ----
__global__ __launch_bounds__(512) void k_kv(const unsigned short* __restrict__ xT,
    const unsigned short* __restrict__ wqp, const float* __restrict__ bias,
    float* __restrict__ kvpart, float* __restrict__ ksumpart){
  int blk = blockIdx.x;                        // b*128 + nt (128-n tile)
  int b = blk >> 7, nt = blk & 127;
  __shared__ unsigned short S[32768];          // 32KB k image + 32KB v image (x tile first)
  int t = threadIdx.x, w = t >> 6, lane = t & 63, lr = lane & 15, lk = lane >> 4;
  short8 wfr[2][4]; float biasv[2];
  #pragma unroll
  for (int rt = 0; rt < 2; ++rt){
    int o = 128 + rt*128 + w*16;
    #pragma unroll
    for (int ks = 0; ks < 4; ++ks)
      wfr[rt][ks] = *(const short8*)(wqp + ((size_t)(b*384 + o + lr))*128 + ks*32 + lk*8);
    biasv[rt] = bias[b*384 + o + lr];
  }
  const unsigned short* src = xT + ((size_t)(b*64 + (nt >> 1)))*32768 + (nt & 1)*16384;
  for (int it = 0; it < 4; ++it){
    int slot = t + it*512;
    *(short8*)(S + slot*8) = *(const short8*)(src + slot*8);
  }
  __syncthreads();
  short4v kpk[8], vpk[8];
  for (int ct = 0; ct < 8; ++ct){
    int nr = ct*16 + lr;
    int kn = keyx(nr);
    short8 xfr[4];
    #pragma unroll
    for (int ks = 0; ks < 4; ++ks)
      xfr[ks] = *(const short8*)(S + nr*128 + (((ks*4 + lk) ^ kn) << 3));
    #pragma unroll
    for (int rt = 0; rt < 2; ++rt){
      floatx4 acc = {0.f,0.f,0.f,0.f};
      #pragma unroll
      for (int ks = 0; ks < 4; ++ks)
        acc = __builtin_amdgcn_mfma_f32_16x16x32_bf16(xfr[ks], wfr[rt][ks], acc, 0,0,0);
      short4v pk;                              // D[n][o]: lane holds o = base+lr, n = ct*16+lk*4+r
      #pragma unroll
      for (int r = 0; r < 4; ++r){
        float v = acc[r] + biasv[rt];
        if (rt == 0) v = elu1(v);
        pk[r] = (short)f2bf(v);
      }
      if (rt == 0) kpk[ct] = pk; else vpk[ct] = pk;
    }
  }
  __syncthreads();
  // build k/v images [128 c][128 n] bf16 (key=(c>>1)&7) with b64 writes (4 consecutive n)
  #pragma unroll
  for (int ct = 0; ct < 8; ++ct){
    int cimg = w*16 + lr;
    int n0 = ct*16 + lk*4;
    int off = cimg*128 + ((((n0 >> 3) ^ ((cimg >> 1) & 7)) << 3) + (n0 & 7));
    *(short4v*)(S + off)         = kpk[ct];
    *(short4v*)(S + 16384 + off) = vpk[ct];
  }
  __syncthreads();
  short8 ones;
  #pragma unroll
  for (int j = 0; j < 8; ++j) ones[j] = (short)0x3F80;
  #pragma unroll
  for (int j = 0; j < 2; ++j){
    int m = w + 8*j;                           // 16 tasks: h x dt x et
    int h = m >> 2, dt = (m >> 1) & 1, et = m & 1;
    int arow = h*32 + dt*16 + lr, brow = h*32 + et*16 + lr;
    int akey = (lr >> 1) & 7;
    floatx4 acc = {0.f,0.f,0.f,0.f}, ks_acc = {0.f,0.f,0.f,0.f};
    #pragma unroll
    for (int ks = 0; ks < 4; ++ks){
      short8 ka = *(const short8*)(S + arow*128 + (((ks*4 + lk) ^ akey) << 3));
      short8 vb = *(const short8*)(S + 16384 + brow*128 + (((ks*4 + lk) ^ akey) << 3));
      acc = __builtin_amdgcn_mfma_f32_16x16x32_bf16(ka, vb, acc, 0,0,0);
      if (et == 0) ks_acc = __builtin_amdgcn_mfma_f32_16x16x32_bf16(ka, ones, ks_acc, 0,0,0);
    }
    float* kvp = kvpart + ((size_t)(blk*4 + h))*1024;
    #pragma unroll
    for (int r = 0; r < 4; ++r)
      kvp[(dt*16 + lk*4 + r)*32 + et*16 + lr] = acc[r];
    if (et == 0 && lr == 0){
      float* ksp = ksumpart + ((size_t)(blk*4 + h))*32;
      #pragma unroll
      for (int r = 0; r < 4; ++r) ksp[dt*16 + lk*4 + r] = ks_acc[r];
    }
  }
}

// ---- K3f: reduce kv/ksum partials; fold kv into w_out:  M[o][h*32+d] = sum_e w2[o][h*32+e]*kv[d][e] ----
__global__ __launch_bounds__(256) void k_kvmfold(const float* __restrict__ kvpart, const float* __restrict__ ksumpart,
    const unsigned short* __restrict__ woutb, unsigned short* __restrict__ Mb, float* __restrict__ ksumF){
  int bh = blockIdx.x, t = threadIdx.x;        // 64 = (b, h)
  int b = bh >> 2, h = bh & 3;
  __shared__ float kvL[1024];
  for (int i = t; i < 1024; i += 256){
    float s = 0.f;
    for (int nt = 0; nt < 128; ++nt) s += kvpart[((size_t)((b*128 + nt)*4 + h))*1024 + i];
    kvL[i] = s;                                // kv[d][e] at d*32+e
  }
  if (t < 32){
    float s = 0.f;
    for (int nt = 0; nt < 128; ++nt) s += ksumpart[((size_t)((b*128 + nt)*4 + h))*32 + t];
    ksumF[b*128 + h*32 + t] = s;
  }
  __syncthreads();
  int o = t >> 1, d0 = (t & 1)*16;
  float w2row[32];
  #pragma unroll
  for (int e = 0; e < 32; ++e) w2row[e] = bf2f(woutb[o*128 + h*32 + e]);
  for (int dd = 0; dd < 16; ++dd){
    int d = d0 + dd;
    float s = 0.f;
    #pragma unroll
    for (int e = 0; e < 32; ++e) s += w2row[e] * kvL[d*32 + e];
    Mb[((size_t)b)*16384 + o*128 + h*32 + d] = f2bf(s);
  }
}

// ---- K4: 512-thread, 128-n tile (32KB LDS): q GEMM -> in-reg denom+scale -> q' image ->
//          swapped M GEMM (n-major D) -> [c][n] hbT vector stores + GN2 partials ----
__global__ __launch_bounds__(512) void k_attn2(const unsigned short* __restrict__ xT,
    const unsigned short* __restrict__ wqp, const float* __restrict__ bias,
    const float* __restrict__ ksumF, const unsigned short* __restrict__ Mb,
    unsigned short* __restrict__ hbT, float* __restrict__ gn2part){
  int blk = blockIdx.x;                        // b*128 + t128
  int b = blk >> 7, t128 = blk & 127;
  __shared__ unsigned short S[16384];          // 32KB: x half-tile image, later q' image
  int t = threadIdx.x, w = t >> 6, lane = t & 63, lr = lane & 15, lk = lane >> 4;
  int rg = w & 3, cg = w >> 2;                 // rg = head; cg = 64-n half of the 128-n tile
  const unsigned short* src = xT + ((size_t)(b*64 + (t128 >> 1)))*32768 + (t128 & 1)*16384;
  for (int it = 0; it < 4; ++it){
    int slot = t + it*512;
    *(short8*)(S + slot*8) = *(const short8*)(src + slot*8);
  }
  // hoisted q-weight fragments for this wave's head (2 row-tiles)
  short8 afr[2][4]; float biasq[2][4], ksL[2][4];
  #pragma unroll
  for (int rtl = 0; rtl < 2; ++rtl){
    int o = rg*32 + rtl*16;
    #pragma unroll
    for (int ks = 0; ks < 4; ++ks)
      afr[rtl][ks] = *(const short8*)(wqp + ((size_t)(b*384 + o + lr))*128 + ks*32 + lk*8);
    #pragma unroll
    for (int r = 0; r < 4; ++r){
      biasq[rtl][r] = bias[b*384 + o + lk*4 + r];
      ksL[rtl][r]   = ksumF[b*128 + o + lk*4 + r];
    }
  }
  __syncthreads();
  // q-GEMM over this wave's 64-n half + in-register denominator + scale
  short4v qpk[2][4];
  #pragma unroll
  for (int ct = 0; ct < 4; ++ct){
    int nr = cg*64 + ct*16 + lr;
    int kn = keyx(nr);
    short8 bfr[4];
    #pragma unroll
    for (int ks = 0; ks < 4; ++ks)
      bfr[ks] = *(const short8*)(S + nr*128 + (((ks*4 + lk) ^ kn) << 3));
    float qv[2][4];
    #pragma unroll
    for (int rtl = 0; rtl < 2; ++rtl){
      floatx4 acc = {0.f,0.f,0.f,0.f};
      #pragma unroll
      for (int ks = 0; ks < 4; ++ks)
        acc = __builtin_amdgcn_mfma_f32_16x16x32_bf16(afr[rtl][ks], bfr[ks], acc, 0,0,0);
      #pragma unroll
      for (int r = 0; r < 4; ++r) qv[rtl][r] = elu1(acc[r] + biasq[rtl][r]);
    }
    float p = 0.f;
    #pragma unroll
    for (int rtl = 0; rtl < 2; ++rtl)
      #pragma unroll
      for (int r = 0; r < 4; ++r) p += ksL[rtl][r] * qv[rtl][r];
    p += __shfl_xor(p, 16);
    p += __shfl_xor(p, 32);                    // sum over lk -> full 32-channel head dot
    float inv = 1.f / (p + 1e-6f);
    #pragma unroll
    for (int rtl = 0; rtl < 2; ++rtl){
      short4v pk;
      #pragma unroll
      for (int r = 0; r < 4; ++r) pk[r] = (short)f2bf(qv[rtl][r] * inv);
      qpk[rtl][ct] = pk;
    }
  }
  // hoist M fragments (wave w -> output rows 16w..16w+16)
  short8 afr2[4];
  #pragma unroll
  for (int ks = 0; ks < 4; ++ks)
    afr2[ks] = *(const short8*)(Mb + ((size_t)b)*16384 + (size_t)(w*16 + lr)*128 + ks*32 + lk*8);
  __syncthreads();                             // all x reads done
  // write q' image [n][c], key n&7
  #pragma unroll
  for (int rtl = 0; rtl < 2; ++rtl){
    int c0 = rg*32 + rtl*16 + lk*4;
    #pragma unroll
    for (int ct = 0; ct < 4; ++ct){
      int n = cg*64 + ct*16 + lr;
      *(short4v*)(S + n*128 + ((((c0 >> 3) ^ (n & 7)) << 3) + (c0 & 7))) = qpk[rtl][ct];
    }
  }
  __syncthreads();
  // Swapped M-GEMM: D[n][c_out]; lane holds c_out = w*16+lr, n-quad = ct*16+lk*4
  unsigned short* hdst = hbT + ((size_t)blk)*16384;   // [c][128 n] tile
  float s1 = 0.f, s2v = 0.f;
  #pragma unroll
  for (int ct = 0; ct < 8; ++ct){
    int nr = ct*16 + lr;
    short8 bfr[4];
    #pragma unroll
    for (int ks = 0; ks < 4; ++ks)
      bfr[ks] = *(const short8*)(S + nr*128 + (((ks*4 + lk) ^ (nr & 7)) << 3));
    floatx4 acc = {0.f,0.f,0.f,0.f};
    #pragma unroll
    for (int ks = 0; ks < 4; ++ks)
      acc = __builtin_amdgcn_mfma_f32_16x16x32_bf16(bfr[ks], afr2[ks], acc, 0,0,0);
    short4v pk;
    #pragma unroll
    for (int r = 0; r < 4; ++r){
      float hv = acc[r];
      pk[r] = (short)f2bf(hv);
      s1 += hv; s2v += hv*hv;
    }
    *(short4v*)(hdst + (w*16 + lr)*128 + ct*16 + lk*4) = pk;
  }
  s1  += __shfl_xor(s1, 16);  s1  += __shfl_xor(s1, 32);
  s2v += __shfl_xor(s2v, 16); s2v += __shfl_xor(s2v, 32);
  if (lane < 16){                              // lk==0 lanes hold channel totals
    int c = w*16 + lr;
    gn2part[((size_t)blk*128 + c)*2 + 0] = s1;
    gn2part[((size_t)blk*128 + c)*2 + 1] = s2v;
  }
}

// ---- K5: GN2 stats (128 t128-tiles per b) ----
__global__ __launch_bounds__(64) void k_gn2stats(const float* __restrict__ gn2part,
    float* __restrict__ mean, float* __restrict__ rstd){
  int b = blockIdx.x >> 5, g = blockIdx.x & 31;
  int lane = threadIdx.x;
  float s = 0.f, s2 = 0.f;
  #pragma unroll
  for (int rr = 0; rr < 2; ++rr){
    int row = lane + rr*64;                    // t128
    const float* p = gn2part + ((size_t)(b*128 + row))*256 + g*8;
    #pragma unroll
    for (int j = 0; j < 4; ++j){ s += p[j*2]; s2 += p[j*2 + 1]; }
  }
  #pragma unroll
  for (int o = 32; o; o >>= 1){ s += __shfl_down(s, o); s2 += __shfl_down(s2, o); }
  if (lane == 0){
    float m = s * (1.f/65536.f);
    float var = s2 * (1.f/65536.f) - m*m;
    mean[blockIdx.x] = m; rstd[blockIdx.x] = rsqrtf(var + 1e-5f);
  }
}

// ---- K6: out = GN2(h) + x  (h: direct vectorized global reads from [c][n] hbT;
//          x: XS staging with 16B-slot rotation (slot+(n>>3))&15 -> ~2-way banks) ----
__global__ __launch_bounds__(256) void k_final(const unsigned short* __restrict__ hbT,
    const unsigned short* __restrict__ xT, float* __restrict__ out,
    const float* __restrict__ mean, const float* __restrict__ rstd,
    const float* __restrict__ g2w, const float* __restrict__ g2b){
  int blk = blockIdx.x;                        // b*128 + t128
  int b = blk >> 7, t128 = blk & 127;
  __shared__ unsigned short XS[16384];
  int t = threadIdx.x;
  const unsigned short* xsrc = xT + ((size_t)(b*64 + (t128 >> 1)))*32768 + (t128 & 1)*16384;
  for (int it = 0; it < 8; ++it){
    int slot = t + it*256;                     // 16B-slot id: n = slot>>4, sl = slot&15
    int n = slot >> 4, sl = slot & 15;
    *(short8*)(XS + n*128 + (((sl + (n >> 3)) & 15) << 3)) = *(const short8*)(xsrc + slot*8);
  }
  __syncthreads();
  const unsigned short* hsrc = hbT + (size_t)blk*16384;
  for (int it = 0; it < 8; ++it){
    int idx = t + it*256;                      // 2048 = 128 c x 16 octets
    int c = idx >> 4, oct = idx & 15;
    int bg = b*32 + (c >> 2);
    float m = mean[bg], r = rstd[bg];
    float sc = r * g2w[c], sh = g2b[c] - m * sc;
    short8 hv = *(const short8*)(hsrc + c*128 + oct*8);   // coalesced 16B global read
    float ov[8];
    #pragma unroll
    for (int j = 0; j < 8; ++j){
      int n = oct*8 + j;
      int sl = (c >> 3) ^ keyx(n);
      unsigned short xv = XS[n*128 + ((((sl + (n >> 3)) & 15) << 3) + (c & 7))];
      ov[j] = bf2f((unsigned short)hv[j])*sc + sh + bf2f(xv);
    }
    float* op = out + ((size_t)(b*128 + c))*HW_ + t128*128 + oct*8;
    float4 o0, o1;
    o0.x = ov[0]; o0.y = ov[1]; o0.z = ov[2]; o0.w = ov[3];
    o1.x = ov[4]; o1.y = ov[5]; o1.z = ov[6]; o1.w = ov[7];
    *(float4*)op = o0; *(float4*)(op + 4) = o1;
  }
}

extern "C" void kernel_launch(void* const* d_in, const int* in_sizes, int n_in,
                              void* d_out, int out_size, void* d_ws, size_t ws_size,
                              hipStream_t stream){
  const float* x    = (const float*)d_in[0];
  const float* g1w  = (const float*)d_in[1];
  const float* g1b  = (const float*)d_in[2];
  const float* wqkv = (const float*)d_in[3];
  const float* wout = (const float*)d_in[4];
  const float* g2w  = (const float*)d_in[5];
  const float* g2b  = (const float*)d_in[6];
  char* ws = (char*)d_ws;
  (void)in_sizes; (void)n_in; (void)out_size; (void)ws_size;

  float* gn1part  = (float*)(ws + 0);                        // 256KB
  float* gn1_mean = (float*)(ws + 262144);
  float* gn1_rstd = (float*)(ws + 264192);
  float* gn2_mean = (float*)(ws + 266240);
  float* gn2_rstd = (float*)(ws + 268288);
  float* bias     = (float*)(ws + 270336);                   // 24KB -> 294912
  unsigned short* woutb = (unsigned short*)(ws + 294912);    // 32KB -> 327680
  float* ksumF    = (float*)(ws + 327680);                   // 8KB  -> 335872
  unsigned short* Mb = (unsigned short*)(ws + 335872);       // 512KB -> 860160
  unsigned short* wqp = (unsigned short*)(ws + 860160);      // 1.5MB -> 2433024
  float* ksumpart = (float*)(ws + 2433024);                  // 1MB -> 3481600
  float* kvpart   = (float*)(ws + 4194304);                  // 32MB -> 37748736
  float* gn2part  = (float*)(ws + 37748736);                 // 2MB -> 39845888
  unsigned short* xT  = (unsigned short*)(ws + 46137344);    // 64MB -> 113246208
  unsigned short* hbT = (unsigned short*)(ws + 113246208);   // 64MB -> 180355072

  k_xprep<<<dim3(1024), dim3(512), 0, stream>>>(x, xT, gn1part);
  k_gn1fin<<<dim3(512), dim3(64), 0, stream>>>(gn1part, gn1_mean, gn1_rstd);
  k_fold<<<dim3(6272), dim3(64), 0, stream>>>(wqkv, wout, g1w, g1b, gn1_mean, gn1_rstd, wqp, bias, woutb);
  k_kv<<<dim3(2048), dim3(512), 0, stream>>>(xT, wqp, bias, kvpart, ksumpart);
  k_kvmfold<<<dim3(64), dim3(256), 0, stream>>>(kvpart, ksumpart, woutb, Mb, ksumF);
  k_attn2<<<dim3(2048), dim3(512), 0, stream>>>(xT, wqp, bias, ksumF, Mb, hbT, gn2part);
  k_gn2stats<<<dim3(512), dim3(64), 0, stream>>>(gn2part, gn2_mean, gn2_rstd);
  k_final<<<dim3(2048), dim3(256), 0, stream>>>(hbT, xT, (float*)d_out, gn2_mean, gn2_rstd, g2w, g2b);
}

// Round 15
// 213.107 us; speedup vs baseline: 1.0156x; 1.0156x over previous
//
#include <hip/hip_runtime.h>

#define B_   16
#define C_   128
#define HW_  16384

typedef __attribute__((ext_vector_type(4))) float  floatx4;
typedef __attribute__((ext_vector_type(8))) short  short8;
typedef __attribute__((ext_vector_type(4))) short  short4v;

static __device__ __forceinline__ unsigned short f2bf(float f){
  unsigned int u = __float_as_uint(f);
  u += 0x7FFFu + ((u >> 16) & 1u);
  return (unsigned short)(u >> 16);
}
static __device__ __forceinline__ float bf2f(unsigned short h){
  return __uint_as_float(((unsigned int)h) << 16);
}
static __device__ __forceinline__ float elu1(float v){
  return v > 0.f ? v + 1.f : __expf(v);
}
// xT swizzle key (period 128 in n, so 128-row half-tiles keep the same key)
static __device__ __forceinline__ int keyx(int n){ return ((n >> 1) & 7) ^ ((n >> 4) & 7); }

// ---- K1: x -> xT (bf16, tile-major [b][tile256][n][c] pre-swizzled LDS image) + GN1 partial stats ----
__global__ __launch_bounds__(512) void k_xprep(const float* __restrict__ x,
    unsigned short* __restrict__ xT, float* __restrict__ gn1part){
  int blk = blockIdx.x;                        // b*64 + tile
  int b = blk >> 6, tile = blk & 63;
  int n0 = tile * 256;
  __shared__ unsigned short XS[32768];
  int t = threadIdx.x, w = t >> 6, l = t & 63;
  float sk[4], sk2[4];
  #pragma unroll
  for (int k = 0; k < 4; ++k){ sk[k] = 0.f; sk2[k] = 0.f; }
  #pragma unroll
  for (int k = 0; k < 4; ++k){
    float4 f4[4];
    #pragma unroll
    for (int j = 0; j < 4; ++j){
      int c = 16*w + 4*k + j;
      f4[j] = *(const float4*)(x + ((size_t)(b*128 + c))*HW_ + n0 + 4*l);
    }
    #pragma unroll
    for (int j = 0; j < 4; ++j){
      sk[k]  += f4[j].x + f4[j].y + f4[j].z + f4[j].w;
      sk2[k] += f4[j].x*f4[j].x + f4[j].y*f4[j].y + f4[j].z*f4[j].z + f4[j].w*f4[j].w;
    }
    int c0 = 16*w + 4*k, cs = c0 >> 3, co = c0 & 7;
    #pragma unroll
    for (int i = 0; i < 4; ++i){
      int n = 4*l + i;
      short4v p;
      #pragma unroll
      for (int j = 0; j < 4; ++j) p[j] = (short)f2bf(((const float*)&f4[j])[i]);
      *(short4v*)(XS + n*128 + (((cs ^ keyx(n)) << 3) + co)) = p;
    }
  }
  #pragma unroll
  for (int k = 0; k < 4; ++k){
    float a = sk[k], q = sk2[k];
    #pragma unroll
    for (int o = 32; o; o >>= 1){ a += __shfl_down(a, o); q += __shfl_down(q, o); }
    if (l == 0){
      gn1part[((size_t)blk)*64 + (4*w + k)*2 + 0] = a;
      gn1part[((size_t)blk)*64 + (4*w + k)*2 + 1] = q;
    }
  }
  __syncthreads();
  unsigned short* dst = xT + ((size_t)blk)*32768;
  for (int it = 0; it < 8; ++it){
    int slot = t + it*512;
    *(short8*)(dst + slot*8) = *(const short8*)(XS + slot*8);
  }
}

// ---- K1f: finalize GN1 stats ----
__global__ __launch_bounds__(64) void k_gn1fin(const float* __restrict__ gn1part,
    float* __restrict__ mean, float* __restrict__ rstd){
  int bg = blockIdx.x;
  int b = bg >> 5, g = bg & 31, l = threadIdx.x;
  const float* p = gn1part + ((size_t)(b*64 + l))*64 + g*2;
  float s = p[0], s2 = p[1];
  #pragma unroll
  for (int o = 32; o; o >>= 1){ s += __shfl_down(s, o); s2 += __shfl_down(s2, o); }
  if (l == 0){
    float m = s * (1.f/65536.f);
    float var = s2 * (1.f/65536.f) - m*m;
    mean[bg] = m; rstd[bg] = rsqrtf(var + 1e-5f);
  }
}

// ---- K2: fold GN1 into qkv weights (per batch), w_out -> bf16 (4 rows/block, 1 wave each) ----
__global__ __launch_bounds__(256) void k_fold(const float* __restrict__ wqkv, const float* __restrict__ wout,
    const float* __restrict__ g1w, const float* __restrict__ g1b,
    const float* __restrict__ mean, const float* __restrict__ rstd,
    unsigned short* __restrict__ wqp, float* __restrict__ bias, unsigned short* __restrict__ woutb){
  int i = blockIdx.x*4 + (threadIdx.x >> 6);   // row index 0..6271
  int l = threadIdx.x & 63;
  if (i < 6144){
    int b = i / 384, o = i % 384;
    float bsum = 0.f;
    #pragma unroll
    for (int j = 0; j < 2; ++j){
      int c = l*2 + j, g = c >> 2;
      float m = mean[b*32 + g], r = rstd[b*32 + g];
      float A  = r * g1w[c];
      float Bc = g1b[c] - m * A;
      float wv = wqkv[o*128 + c];
      wqp[((size_t)(b*384 + o))*128 + c] = f2bf(wv * A);
      bsum += wv * Bc;
    }
    #pragma unroll
    for (int o2 = 32; o2; o2 >>= 1) bsum += __shfl_down(bsum, o2);
    if (l == 0) bias[b*384 + o] = bsum;
  } else {
    int r = i - 6144;
    #pragma unroll
    for (int j = 0; j < 2; ++j){ int c = l*2 + j; woutb[r*128 + c] = f2bf(wout[r*128 + c]); }
  }
}

// ---- K3: k,v GEMM (operand-swapped -> n-major D, b64 image writes) + 2-half VGPR-accumulated
//          kv/ksum reduction (R10/R13 proven) ----
__global__ __launch_bounds__(512) void k_kv(const unsigned short* __restrict__ xT,
    const unsigned short* __restrict__ wqp, const float* __restrict__ bias,
    float* __restrict__ kvpart, float* __restrict__ ksumpart){
  int blk = blockIdx.x;                        // b*64 + pt (256-n tile; 2 halves)
  int b = blk >> 6;
  __shared__ unsigned short S[32768];          // 32KB k image + 32KB v image (x tile first)
  int t = threadIdx.x, w = t >> 6, lane = t & 63, lr = lane & 15, lk = lane >> 4;
  short8 wfr[2][4]; float biasv[2];
  #pragma unroll
  for (int rt = 0; rt < 2; ++rt){
    int o = 128 + rt*128 + w*16;
    #pragma unroll
    for (int ks = 0; ks < 4; ++ks)
      wfr[rt][ks] = *(const short8*)(wqp + ((size_t)(b*384 + o + lr))*128 + ks*32 + lk*8);
    biasv[rt] = bias[b*384 + o + lr];
  }
  short8 ones;
  #pragma unroll
  for (int j = 0; j < 8; ++j) ones[j] = (short)0x3F80;
  floatx4 accA = {0,0,0,0}, accB = {0,0,0,0}, ksaA = {0,0,0,0}, ksaB = {0,0,0,0};
  for (int half = 0; half < 2; ++half){
    const unsigned short* src = xT + ((size_t)blk)*32768 + half*16384;
    for (int it = 0; it < 4; ++it){
      int slot = t + it*512;
      *(short8*)(S + slot*8) = *(const short8*)(src + slot*8);
    }
    __syncthreads();
    short4v kpk[8], vpk[8];
    for (int ct = 0; ct < 8; ++ct){
      int nr = ct*16 + lr;
      int kn = keyx(nr);
      short8 xfr[4];
      #pragma unroll
      for (int ks = 0; ks < 4; ++ks)
        xfr[ks] = *(const short8*)(S + nr*128 + (((ks*4 + lk) ^ kn) << 3));
      #pragma unroll
      for (int rt = 0; rt < 2; ++rt){
        floatx4 acc = {0.f,0.f,0.f,0.f};
        #pragma unroll
        for (int ks = 0; ks < 4; ++ks)
          acc = __builtin_amdgcn_mfma_f32_16x16x32_bf16(xfr[ks], wfr[rt][ks], acc, 0,0,0);
        short4v pk;                            // D[n][o]: lane holds o = base+lr, n = ct*16+lk*4+r
        #pragma unroll
        for (int r = 0; r < 4; ++r){
          float v = acc[r] + biasv[rt];
          if (rt == 0) v = elu1(v);
          pk[r] = (short)f2bf(v);
        }
        if (rt == 0) kpk[ct] = pk; else vpk[ct] = pk;
      }
    }
    __syncthreads();
    #pragma unroll
    for (int ct = 0; ct < 8; ++ct){
      int cimg = w*16 + lr;
      int n0 = ct*16 + lk*4;
      int off = cimg*128 + ((((n0 >> 3) ^ ((cimg >> 1) & 7)) << 3) + (n0 & 7));
      *(short4v*)(S + off)         = kpk[ct];
      *(short4v*)(S + 16384 + off) = vpk[ct];
    }
    __syncthreads();
    #pragma unroll
    for (int j = 0; j < 2; ++j){
      int m = w + 8*j;                         // 16 tasks: h x dt x et
      int h = m >> 2, dt = (m >> 1) & 1, et = m & 1;
      int arow = h*32 + dt*16 + lr, brow = h*32 + et*16 + lr;
      int akey = (lr >> 1) & 7;
      #pragma unroll
      for (int ks = 0; ks < 4; ++ks){
        short8 ka = *(const short8*)(S + arow*128 + (((ks*4 + lk) ^ akey) << 3));
        short8 vb = *(const short8*)(S + 16384 + brow*128 + (((ks*4 + lk) ^ akey) << 3));
        if (j == 0){
          accA = __builtin_amdgcn_mfma_f32_16x16x32_bf16(ka, vb, accA, 0,0,0);
          if (et == 0) ksaA = __builtin_amdgcn_mfma_f32_16x16x32_bf16(ka, ones, ksaA, 0,0,0);
        } else {
          accB = __builtin_amdgcn_mfma_f32_16x16x32_bf16(ka, vb, accB, 0,0,0);
          if (et == 0) ksaB = __builtin_amdgcn_mfma_f32_16x16x32_bf16(ka, ones, ksaB, 0,0,0);
        }
      }
    }
    __syncthreads();
  }
  #pragma unroll
  for (int j = 0; j < 2; ++j){
    int m = w + 8*j;
    int h = m >> 2, dt = (m >> 1) & 1, et = m & 1;
    floatx4 acc = j ? accB : accA, ksa = j ? ksaB : ksaA;
    float* kvp = kvpart + ((size_t)(blk*4 + h))*1024;
    #pragma unroll
    for (int r = 0; r < 4; ++r)
      kvp[(dt*16 + lk*4 + r)*32 + et*16 + lr] = acc[r];
    if (et == 0 && lr == 0){
      float* ksp = ksumpart + ((size_t)(blk*4 + h))*32;
      #pragma unroll
      for (int r = 0; r < 4; ++r) ksp[dt*16 + lk*4 + r] = ksa[r];
    }
  }
}

// ---- K3f: reduce kv/ksum partials; fold kv into w_out:  M[o][h*32+d] = sum_e w2[o][h*32+e]*kv[d][e] ----
__global__ __launch_bounds__(256) void k_kvmfold(const float* __restrict__ kvpart, const float* __restrict__ ksumpart,
    const unsigned short* __restrict__ woutb, unsigned short* __restrict__ Mb, float* __restrict__ ksumF){
  int bh = blockIdx.x, t = threadIdx.x;        // 64 = (b, h)
  int b = bh >> 2, h = bh & 3;
  __shared__ float kvL[1024];
  for (int i = t; i < 1024; i += 256){
    float s = 0.f;
    for (int nt = 0; nt < 64; ++nt) s += kvpart[((size_t)((b*64 + nt)*4 + h))*1024 + i];
    kvL[i] = s;                                // kv[d][e] at d*32+e
  }
  if (t < 32){
    float s = 0.f;
    for (int nt = 0; nt < 64; ++nt) s += ksumpart[((size_t)((b*64 + nt)*4 + h))*32 + t];
    ksumF[b*128 + h*32 + t] = s;
  }
  __syncthreads();
  int o = t >> 1, d0 = (t & 1)*16;
  float w2row[32];
  #pragma unroll
  for (int e = 0; e < 32; ++e) w2row[e] = bf2f(woutb[o*128 + h*32 + e]);
  for (int dd = 0; dd < 16; ++dd){
    int d = d0 + dd;
    float s = 0.f;
    #pragma unroll
    for (int e = 0; e < 32; ++e) s += w2row[e] * kvL[d*32 + e];
    Mb[((size_t)b)*16384 + o*128 + h*32 + d] = f2bf(s);
  }
}

// ---- K4: 512-thread, 128-n tile (32KB LDS): q GEMM -> in-reg denom+scale -> q' image ->
//          swapped M GEMM (n-major D) -> [c][n] hbT vector stores + GN2 partials ----
__global__ __launch_bounds__(512) void k_attn2(const unsigned short* __restrict__ xT,
    const unsigned short* __restrict__ wqp, const float* __restrict__ bias,
    const float* __restrict__ ksumF, const unsigned short* __restrict__ Mb,
    unsigned short* __restrict__ hbT, float* __restrict__ gn2part){
  int blk = blockIdx.x;                        // b*128 + t128
  int b = blk >> 7, t128 = blk & 127;
  __shared__ unsigned short S[16384];          // 32KB: x half-tile image, later q' image
  int t = threadIdx.x, w = t >> 6, lane = t & 63, lr = lane & 15, lk = lane >> 4;
  int rg = w & 3, cg = w >> 2;                 // rg = head; cg = 64-n half of the 128-n tile
  const unsigned short* src = xT + ((size_t)(b*64 + (t128 >> 1)))*32768 + (t128 & 1)*16384;
  for (int it = 0; it < 4; ++it){
    int slot = t + it*512;
    *(short8*)(S + slot*8) = *(const short8*)(src + slot*8);
  }
  // hoisted q-weight fragments for this wave's head (2 row-tiles)
  short8 afr[2][4]; float biasq[2][4], ksL[2][4];
  #pragma unroll
  for (int rtl = 0; rtl < 2; ++rtl){
    int o = rg*32 + rtl*16;
    #pragma unroll
    for (int ks = 0; ks < 4; ++ks)
      afr[rtl][ks] = *(const short8*)(wqp + ((size_t)(b*384 + o + lr))*128 + ks*32 + lk*8);
    #pragma unroll
    for (int r = 0; r < 4; ++r){
      biasq[rtl][r] = bias[b*384 + o + lk*4 + r];
      ksL[rtl][r]   = ksumF[b*128 + o + lk*4 + r];
    }
  }
  __syncthreads();
  // q-GEMM over this wave's 64-n half + in-register denominator + scale
  short4v qpk[2][4];
  #pragma unroll
  for (int ct = 0; ct < 4; ++ct){
    int nr = cg*64 + ct*16 + lr;
    int kn = keyx(nr);
    short8 bfr[4];
    #pragma unroll
    for (int ks = 0; ks < 4; ++ks)
      bfr[ks] = *(const short8*)(S + nr*128 + (((ks*4 + lk) ^ kn) << 3));
    float qv[2][4];
    #pragma unroll
    for (int rtl = 0; rtl < 2; ++rtl){
      floatx4 acc = {0.f,0.f,0.f,0.f};
      #pragma unroll
      for (int ks = 0; ks < 4; ++ks)
        acc = __builtin_amdgcn_mfma_f32_16x16x32_bf16(afr[rtl][ks], bfr[ks], acc, 0,0,0);
      #pragma unroll
      for (int r = 0; r < 4; ++r) qv[rtl][r] = elu1(acc[r] + biasq[rtl][r]);
    }
    float p = 0.f;
    #pragma unroll
    for (int rtl = 0; rtl < 2; ++rtl)
      #pragma unroll
      for (int r = 0; r < 4; ++r) p += ksL[rtl][r] * qv[rtl][r];
    p += __shfl_xor(p, 16);
    p += __shfl_xor(p, 32);                    // sum over lk -> full 32-channel head dot
    float inv = 1.f / (p + 1e-6f);
    #pragma unroll
    for (int rtl = 0; rtl < 2; ++rtl){
      short4v pk;
      #pragma unroll
      for (int r = 0; r < 4; ++r) pk[r] = (short)f2bf(qv[rtl][r] * inv);
      qpk[rtl][ct] = pk;
    }
  }
  // hoist M fragments (wave w -> output rows 16w..16w+16)
  short8 afr2[4];
  #pragma unroll
  for (int ks = 0; ks < 4; ++ks)
    afr2[ks] = *(const short8*)(Mb + ((size_t)b)*16384 + (size_t)(w*16 + lr)*128 + ks*32 + lk*8);
  __syncthreads();                             // all x reads done
  // write q' image [n][c], key n&7
  #pragma unroll
  for (int rtl = 0; rtl < 2; ++rtl){
    int c0 = rg*32 + rtl*16 + lk*4;
    #pragma unroll
    for (int ct = 0; ct < 4; ++ct){
      int n = cg*64 + ct*16 + lr;
      *(short4v*)(S + n*128 + ((((c0 >> 3) ^ (n & 7)) << 3) + (c0 & 7))) = qpk[rtl][ct];
    }
  }
  __syncthreads();
  // Swapped M-GEMM: D[n][c_out]; lane holds c_out = w*16+lr, n-quad = ct*16+lk*4
  unsigned short* hdst = hbT + ((size_t)blk)*16384;   // [c][128 n] tile
  float s1 = 0.f, s2v = 0.f;
  #pragma unroll
  for (int ct = 0; ct < 8; ++ct){
    int nr = ct*16 + lr;
    short8 bfr[4];
    #pragma unroll
    for (int ks = 0; ks < 4; ++ks)
      bfr[ks] = *(const short8*)(S + nr*128 + (((ks*4 + lk) ^ (nr & 7)) << 3));
    floatx4 acc = {0.f,0.f,0.f,0.f};
    #pragma unroll
    for (int ks = 0; ks < 4; ++ks)
      acc = __builtin_amdgcn_mfma_f32_16x16x32_bf16(bfr[ks], afr2[ks], acc, 0,0,0);
    short4v pk;
    #pragma unroll
    for (int r = 0; r < 4; ++r){
      float hv = acc[r];
      pk[r] = (short)f2bf(hv);
      s1 += hv; s2v += hv*hv;
    }
    *(short4v*)(hdst + (w*16 + lr)*128 + ct*16 + lk*4) = pk;
  }
  s1  += __shfl_xor(s1, 16);  s1  += __shfl_xor(s1, 32);
  s2v += __shfl_xor(s2v, 16); s2v += __shfl_xor(s2v, 32);
  if (lane < 16){                              // lk==0 lanes hold channel totals
    int c = w*16 + lr;
    gn2part[((size_t)blk*128 + c)*2 + 0] = s1;
    gn2part[((size_t)blk*128 + c)*2 + 1] = s2v;
  }
}

// ---- K5: GN2 stats (128 t128-tiles per b) ----
__global__ __launch_bounds__(64) void k_gn2stats(const float* __restrict__ gn2part,
    float* __restrict__ mean, float* __restrict__ rstd){
  int b = blockIdx.x >> 5, g = blockIdx.x & 31;
  int lane = threadIdx.x;
  float s = 0.f, s2 = 0.f;
  #pragma unroll
  for (int rr = 0; rr < 2; ++rr){
    int row = lane + rr*64;                    // t128
    const float* p = gn2part + ((size_t)(b*128 + row))*256 + g*8;
    #pragma unroll
    for (int j = 0; j < 4; ++j){ s += p[j*2]; s2 += p[j*2 + 1]; }
  }
  #pragma unroll
  for (int o = 32; o; o >>= 1){ s += __shfl_down(s, o); s2 += __shfl_down(s2, o); }
  if (lane == 0){
    float m = s * (1.f/65536.f);
    float var = s2 * (1.f/65536.f) - m*m;
    mean[blockIdx.x] = m; rstd[blockIdx.x] = rsqrtf(var + 1e-5f);
  }
}

// ---- K6: out = GN2(h) + x  (h: direct vectorized global reads from [c][n] hbT;
//          x: XS staging with 16B-slot rotation (slot+(n>>3))&15 -> ~2-way banks) ----
__global__ __launch_bounds__(256) void k_final(const unsigned short* __restrict__ hbT,
    const unsigned short* __restrict__ xT, float* __restrict__ out,
    const float* __restrict__ mean, const float* __restrict__ rstd,
    const float* __restrict__ g2w, const float* __restrict__ g2b){
  int blk = blockIdx.x;                        // b*128 + t128
  int b = blk >> 7, t128 = blk & 127;
  __shared__ unsigned short XS[16384];
  int t = threadIdx.x;
  const unsigned short* xsrc = xT + ((size_t)(b*64 + (t128 >> 1)))*32768 + (t128 & 1)*16384;
  for (int it = 0; it < 8; ++it){
    int slot = t + it*256;                     // 16B-slot id: n = slot>>4, sl = slot&15
    int n = slot >> 4, sl = slot & 15;
    *(short8*)(XS + n*128 + (((sl + (n >> 3)) & 15) << 3)) = *(const short8*)(xsrc + slot*8);
  }
  __syncthreads();
  const unsigned short* hsrc = hbT + (size_t)blk*16384;
  for (int it = 0; it < 8; ++it){
    int idx = t + it*256;                      // 2048 = 128 c x 16 octets
    int c = idx >> 4, oct = idx & 15;
    int bg = b*32 + (c >> 2);
    float m = mean[bg], r = rstd[bg];
    float sc = r * g2w[c], sh = g2b[c] - m * sc;
    short8 hv = *(const short8*)(hsrc + c*128 + oct*8);   // coalesced 16B global read
    float ov[8];
    #pragma unroll
    for (int j = 0; j < 8; ++j){
      int n = oct*8 + j;
      int sl = (c >> 3) ^ keyx(n);
      unsigned short xv = XS[n*128 + ((((sl + (n >> 3)) & 15) << 3) + (c & 7))];
      ov[j] = bf2f((unsigned short)hv[j])*sc + sh + bf2f(xv);
    }
    float* op = out + ((size_t)(b*128 + c))*HW_ + t128*128 + oct*8;
    float4 o0, o1;
    o0.x = ov[0]; o0.y = ov[1]; o0.z = ov[2]; o0.w = ov[3];
    o1.x = ov[4]; o1.y = ov[5]; o1.z = ov[6]; o1.w = ov[7];
    *(float4*)op = o0; *(float4*)(op + 4) = o1;
  }
}

extern "C" void kernel_launch(void* const* d_in, const int* in_sizes, int n_in,
                              void* d_out, int out_size, void* d_ws, size_t ws_size,
                              hipStream_t stream){
  const float* x    = (const float*)d_in[0];
  const float* g1w  = (const float*)d_in[1];
  const float* g1b  = (const float*)d_in[2];
  const float* wqkv = (const float*)d_in[3];
  const float* wout = (const float*)d_in[4];
  const float* g2w  = (const float*)d_in[5];
  const float* g2b  = (const float*)d_in[6];
  char* ws = (char*)d_ws;
  (void)in_sizes; (void)n_in; (void)out_size; (void)ws_size;

  float* gn1part  = (float*)(ws + 0);                        // 256KB
  float* gn1_mean = (float*)(ws + 262144);
  float* gn1_rstd = (float*)(ws + 264192);
  float* gn2_mean = (float*)(ws + 266240);
  float* gn2_rstd = (float*)(ws + 268288);
  float* bias     = (float*)(ws + 270336);                   // 24KB -> 294912
  unsigned short* woutb = (unsigned short*)(ws + 294912);    // 32KB -> 327680
  float* ksumF    = (float*)(ws + 327680);                   // 8KB  -> 335872
  unsigned short* Mb = (unsigned short*)(ws + 335872);       // 512KB -> 860160
  unsigned short* wqp = (unsigned short*)(ws + 860160);      // 1.5MB -> 2433024
  float* ksumpart = (float*)(ws + 2433024);                  // 512KB -> 2957312
  float* kvpart   = (float*)(ws + 4194304);                  // 16MB -> 20971520
  float* gn2part  = (float*)(ws + 37748736);                 // 2MB -> 39845888
  unsigned short* xT  = (unsigned short*)(ws + 46137344);    // 64MB -> 113246208
  unsigned short* hbT = (unsigned short*)(ws + 113246208);   // 64MB -> 180355072

  k_xprep<<<dim3(1024), dim3(512), 0, stream>>>(x, xT, gn1part);
  k_gn1fin<<<dim3(512), dim3(64), 0, stream>>>(gn1part, gn1_mean, gn1_rstd);
  k_fold<<<dim3(1568), dim3(256), 0, stream>>>(wqkv, wout, g1w, g1b, gn1_mean, gn1_rstd, wqp, bias, woutb);
  k_kv<<<dim3(1024), dim3(512), 0, stream>>>(xT, wqp, bias, kvpart, ksumpart);
  k_kvmfold<<<dim3(64), dim3(256), 0, stream>>>(kvpart, ksumpart, woutb, Mb, ksumF);
  k_attn2<<<dim3(2048), dim3(512), 0, stream>>>(xT, wqp, bias, ksumF, Mb, hbT, gn2part);
  k_gn2stats<<<dim3(512), dim3(64), 0, stream>>>(gn2part, gn2_mean, gn2_rstd);
  k_final<<<dim3(2048), dim3(256), 0, stream>>>(hbT, xT, (float*)d_out, gn2_mean, gn2_rstd, g2w, g2b);
}

// Round 16
// 213.053 us; speedup vs baseline: 1.0159x; 1.0003x over previous
//
#include <hip/hip_runtime.h>

#define B_   16
#define C_   128
#define HW_  16384

typedef __attribute__((ext_vector_type(4))) float  floatx4;
typedef __attribute__((ext_vector_type(8))) short  short8;
typedef __attribute__((ext_vector_type(4))) short  short4v;

#define GLDS16(g, l) __builtin_amdgcn_global_load_lds( \
    (const __attribute__((address_space(1))) void*)(g), \
    (__attribute__((address_space(3))) void*)(l), 16, 0, 0)

static __device__ __forceinline__ unsigned short f2bf(float f){
  unsigned int u = __float_as_uint(f);
  u += 0x7FFFu + ((u >> 16) & 1u);
  return (unsigned short)(u >> 16);
}
static __device__ __forceinline__ float bf2f(unsigned short h){
  return __uint_as_float(((unsigned int)h) << 16);
}
static __device__ __forceinline__ float elu1(float v){
  return v > 0.f ? v + 1.f : __expf(v);
}
// xT swizzle key (period 128 in n, so 128-row half-tiles keep the same key)
static __device__ __forceinline__ int keyx(int n){ return ((n >> 1) & 7) ^ ((n >> 4) & 7); }

// ---- K1: x -> xT (bf16, tile-major [b][tile256][n][c] pre-swizzled LDS image) + GN1 partial stats ----
__global__ __launch_bounds__(512) void k_xprep(const float* __restrict__ x,
    unsigned short* __restrict__ xT, float* __restrict__ gn1part){
  int blk = blockIdx.x;                        // b*64 + tile
  int b = blk >> 6, tile = blk & 63;
  int n0 = tile * 256;
  __shared__ unsigned short XS[32768];
  int t = threadIdx.x, w = t >> 6, l = t & 63;
  float sk[4], sk2[4];
  #pragma unroll
  for (int k = 0; k < 4; ++k){ sk[k] = 0.f; sk2[k] = 0.f; }
  #pragma unroll
  for (int k = 0; k < 4; ++k){
    float4 f4[4];
    #pragma unroll
    for (int j = 0; j < 4; ++j){
      int c = 16*w + 4*k + j;
      f4[j] = *(const float4*)(x + ((size_t)(b*128 + c))*HW_ + n0 + 4*l);
    }
    #pragma unroll
    for (int j = 0; j < 4; ++j){
      sk[k]  += f4[j].x + f4[j].y + f4[j].z + f4[j].w;
      sk2[k] += f4[j].x*f4[j].x + f4[j].y*f4[j].y + f4[j].z*f4[j].z + f4[j].w*f4[j].w;
    }
    int c0 = 16*w + 4*k, cs = c0 >> 3, co = c0 & 7;
    #pragma unroll
    for (int i = 0; i < 4; ++i){
      int n = 4*l + i;
      short4v p;
      #pragma unroll
      for (int j = 0; j < 4; ++j) p[j] = (short)f2bf(((const float*)&f4[j])[i]);
      *(short4v*)(XS + n*128 + (((cs ^ keyx(n)) << 3) + co)) = p;
    }
  }
  #pragma unroll
  for (int k = 0; k < 4; ++k){
    float a = sk[k], q = sk2[k];
    #pragma unroll
    for (int o = 32; o; o >>= 1){ a += __shfl_down(a, o); q += __shfl_down(q, o); }
    if (l == 0){
      gn1part[((size_t)blk)*64 + (4*w + k)*2 + 0] = a;
      gn1part[((size_t)blk)*64 + (4*w + k)*2 + 1] = q;
    }
  }
  __syncthreads();
  unsigned short* dst = xT + ((size_t)blk)*32768;
  for (int it = 0; it < 8; ++it){
    int slot = t + it*512;
    *(short8*)(dst + slot*8) = *(const short8*)(XS + slot*8);
  }
}

// ---- K1f: finalize GN1 stats ----
__global__ __launch_bounds__(64) void k_gn1fin(const float* __restrict__ gn1part,
    float* __restrict__ mean, float* __restrict__ rstd){
  int bg = blockIdx.x;
  int b = bg >> 5, g = bg & 31, l = threadIdx.x;
  const float* p = gn1part + ((size_t)(b*64 + l))*64 + g*2;
  float s = p[0], s2 = p[1];
  #pragma unroll
  for (int o = 32; o; o >>= 1){ s += __shfl_down(s, o); s2 += __shfl_down(s2, o); }
  if (l == 0){
    float m = s * (1.f/65536.f);
    float var = s2 * (1.f/65536.f) - m*m;
    mean[bg] = m; rstd[bg] = rsqrtf(var + 1e-5f);
  }
}

// ---- K2: fold GN1 into qkv weights (per batch), w_out -> bf16 (4 rows/block, 1 wave each) ----
__global__ __launch_bounds__(256) void k_fold(const float* __restrict__ wqkv, const float* __restrict__ wout,
    const float* __restrict__ g1w, const float* __restrict__ g1b,
    const float* __restrict__ mean, const float* __restrict__ rstd,
    unsigned short* __restrict__ wqp, float* __restrict__ bias, unsigned short* __restrict__ woutb){
  int i = blockIdx.x*4 + (threadIdx.x >> 6);   // row index 0..6271
  int l = threadIdx.x & 63;
  if (i < 6144){
    int b = i / 384, o = i % 384;
    float bsum = 0.f;
    #pragma unroll
    for (int j = 0; j < 2; ++j){
      int c = l*2 + j, g = c >> 2;
      float m = mean[b*32 + g], r = rstd[b*32 + g];
      float A  = r * g1w[c];
      float Bc = g1b[c] - m * A;
      float wv = wqkv[o*128 + c];
      wqp[((size_t)(b*384 + o))*128 + c] = f2bf(wv * A);
      bsum += wv * Bc;
    }
    #pragma unroll
    for (int o2 = 32; o2; o2 >>= 1) bsum += __shfl_down(bsum, o2);
    if (l == 0) bias[b*384 + o] = bsum;
  } else {
    int r = i - 6144;
    #pragma unroll
    for (int j = 0; j < 2; ++j){ int c = l*2 + j; woutb[r*128 + c] = f2bf(wout[r*128 + c]); }
  }
}

// ---- K3: k,v GEMM (operand-swapped -> n-major D, b64 image writes) + 2-half VGPR-accumulated
//          kv/ksum reduction; staging via global_load_lds ----
__global__ __launch_bounds__(512) void k_kv(const unsigned short* __restrict__ xT,
    const unsigned short* __restrict__ wqp, const float* __restrict__ bias,
    float* __restrict__ kvpart, float* __restrict__ ksumpart){
  int blk = blockIdx.x;                        // b*64 + pt (256-n tile; 2 halves)
  int b = blk >> 6;
  __shared__ unsigned short S[32768];          // 32KB k image + 32KB v image (x tile first)
  int t = threadIdx.x, w = t >> 6, lane = t & 63, lr = lane & 15, lk = lane >> 4;
  short8 wfr[2][4]; float biasv[2];
  #pragma unroll
  for (int rt = 0; rt < 2; ++rt){
    int o = 128 + rt*128 + w*16;
    #pragma unroll
    for (int ks = 0; ks < 4; ++ks)
      wfr[rt][ks] = *(const short8*)(wqp + ((size_t)(b*384 + o + lr))*128 + ks*32 + lk*8);
    biasv[rt] = bias[b*384 + o + lr];
  }
  short8 ones;
  #pragma unroll
  for (int j = 0; j < 8; ++j) ones[j] = (short)0x3F80;
  floatx4 accA = {0,0,0,0}, accB = {0,0,0,0}, ksaA = {0,0,0,0}, ksaB = {0,0,0,0};
  for (int half = 0; half < 2; ++half){
    const unsigned short* src = xT + ((size_t)blk)*32768 + half*16384;
    #pragma unroll
    for (int it = 0; it < 4; ++it){
      int slot = t + it*512;
      GLDS16(src + slot*8, S + slot*8);        // direct global->LDS, 16B/lane, linear dest
    }
    __syncthreads();
    short4v kpk[8], vpk[8];
    for (int ct = 0; ct < 8; ++ct){
      int nr = ct*16 + lr;
      int kn = keyx(nr);
      short8 xfr[4];
      #pragma unroll
      for (int ks = 0; ks < 4; ++ks)
        xfr[ks] = *(const short8*)(S + nr*128 + (((ks*4 + lk) ^ kn) << 3));
      #pragma unroll
      for (int rt = 0; rt < 2; ++rt){
        floatx4 acc = {0.f,0.f,0.f,0.f};
        #pragma unroll
        for (int ks = 0; ks < 4; ++ks)
          acc = __builtin_amdgcn_mfma_f32_16x16x32_bf16(xfr[ks], wfr[rt][ks], acc, 0,0,0);
        short4v pk;                            // D[n][o]: lane holds o = base+lr, n = ct*16+lk*4+r
        #pragma unroll
        for (int r = 0; r < 4; ++r){
          float v = acc[r] + biasv[rt];
          if (rt == 0) v = elu1(v);
          pk[r] = (short)f2bf(v);
        }
        if (rt == 0) kpk[ct] = pk; else vpk[ct] = pk;
      }
    }
    __syncthreads();
    #pragma unroll
    for (int ct = 0; ct < 8; ++ct){
      int cimg = w*16 + lr;
      int n0 = ct*16 + lk*4;
      int off = cimg*128 + ((((n0 >> 3) ^ ((cimg >> 1) & 7)) << 3) + (n0 & 7));
      *(short4v*)(S + off)         = kpk[ct];
      *(short4v*)(S + 16384 + off) = vpk[ct];
    }
    __syncthreads();
    #pragma unroll
    for (int j = 0; j < 2; ++j){
      int m = w + 8*j;                         // 16 tasks: h x dt x et
      int h = m >> 2, dt = (m >> 1) & 1, et = m & 1;
      int arow = h*32 + dt*16 + lr, brow = h*32 + et*16 + lr;
      int akey = (lr >> 1) & 7;
      #pragma unroll
      for (int ks = 0; ks < 4; ++ks){
        short8 ka = *(const short8*)(S + arow*128 + (((ks*4 + lk) ^ akey) << 3));
        short8 vb = *(const short8*)(S + 16384 + brow*128 + (((ks*4 + lk) ^ akey) << 3));
        if (j == 0){
          accA = __builtin_amdgcn_mfma_f32_16x16x32_bf16(ka, vb, accA, 0,0,0);
          if (et == 0) ksaA = __builtin_amdgcn_mfma_f32_16x16x32_bf16(ka, ones, ksaA, 0,0,0);
        } else {
          accB = __builtin_amdgcn_mfma_f32_16x16x32_bf16(ka, vb, accB, 0,0,0);
          if (et == 0) ksaB = __builtin_amdgcn_mfma_f32_16x16x32_bf16(ka, ones, ksaB, 0,0,0);
        }
      }
    }
    __syncthreads();
  }
  #pragma unroll
  for (int j = 0; j < 2; ++j){
    int m = w + 8*j;
    int h = m >> 2, dt = (m >> 1) & 1, et = m & 1;
    floatx4 acc = j ? accB : accA, ksa = j ? ksaB : ksaA;
    float* kvp = kvpart + ((size_t)(blk*4 + h))*1024;
    #pragma unroll
    for (int r = 0; r < 4; ++r)
      kvp[(dt*16 + lk*4 + r)*32 + et*16 + lr] = acc[r];
    if (et == 0 && lr == 0){
      float* ksp = ksumpart + ((size_t)(blk*4 + h))*32;
      #pragma unroll
      for (int r = 0; r < 4; ++r) ksp[dt*16 + lk*4 + r] = ksa[r];
    }
  }
}

// ---- K3f: reduce kv/ksum partials; fold kv into w_out:  M[o][h*32+d] = sum_e w2[o][h*32+e]*kv[d][e] ----
__global__ __launch_bounds__(256) void k_kvmfold(const float* __restrict__ kvpart, const float* __restrict__ ksumpart,
    const unsigned short* __restrict__ woutb, unsigned short* __restrict__ Mb, float* __restrict__ ksumF){
  int bh = blockIdx.x, t = threadIdx.x;        // 64 = (b, h)
  int b = bh >> 2, h = bh & 3;
  __shared__ float kvL[1024];
  for (int i = t; i < 1024; i += 256){
    float s = 0.f;
    for (int nt = 0; nt < 64; ++nt) s += kvpart[((size_t)((b*64 + nt)*4 + h))*1024 + i];
    kvL[i] = s;                                // kv[d][e] at d*32+e
  }
  if (t < 32){
    float s = 0.f;
    for (int nt = 0; nt < 64; ++nt) s += ksumpart[((size_t)((b*64 + nt)*4 + h))*32 + t];
    ksumF[b*128 + h*32 + t] = s;
  }
  __syncthreads();
  int o = t >> 1, d0 = (t & 1)*16;
  float w2row[32];
  #pragma unroll
  for (int e = 0; e < 32; ++e) w2row[e] = bf2f(woutb[o*128 + h*32 + e]);
  for (int dd = 0; dd < 16; ++dd){
    int d = d0 + dd;
    float s = 0.f;
    #pragma unroll
    for (int e = 0; e < 32; ++e) s += w2row[e] * kvL[d*32 + e];
    Mb[((size_t)b)*16384 + o*128 + h*32 + d] = f2bf(s);
  }
}

// ---- K4: 512-thread, 128-n tile (32KB LDS): global_load_lds staging -> q GEMM -> in-reg denom
//          -> q' image -> swapped M GEMM (n-major D) -> [c][n] hbT vector stores + GN2 partials ----
__global__ __launch_bounds__(512) void k_attn2(const unsigned short* __restrict__ xT,
    const unsigned short* __restrict__ wqp, const float* __restrict__ bias,
    const float* __restrict__ ksumF, const unsigned short* __restrict__ Mb,
    unsigned short* __restrict__ hbT, float* __restrict__ gn2part){
  int blk = blockIdx.x;                        // b*128 + t128
  int b = blk >> 7, t128 = blk & 127;
  __shared__ unsigned short S[16384];          // 32KB: x half-tile image, later q' image
  int t = threadIdx.x, w = t >> 6, lane = t & 63, lr = lane & 15, lk = lane >> 4;
  int rg = w & 3, cg = w >> 2;                 // rg = head; cg = 64-n half of the 128-n tile
  const unsigned short* src = xT + ((size_t)(b*64 + (t128 >> 1)))*32768 + (t128 & 1)*16384;
  #pragma unroll
  for (int it = 0; it < 4; ++it){
    int slot = t + it*512;
    GLDS16(src + slot*8, S + slot*8);          // direct global->LDS, linear dest
  }
  // hoisted q-weight fragments for this wave's head (2 row-tiles)
  short8 afr[2][4]; float biasq[2][4], ksL[2][4];
  #pragma unroll
  for (int rtl = 0; rtl < 2; ++rtl){
    int o = rg*32 + rtl*16;
    #pragma unroll
    for (int ks = 0; ks < 4; ++ks)
      afr[rtl][ks] = *(const short8*)(wqp + ((size_t)(b*384 + o + lr))*128 + ks*32 + lk*8);
    #pragma unroll
    for (int r = 0; r < 4; ++r){
      biasq[rtl][r] = bias[b*384 + o + lk*4 + r];
      ksL[rtl][r]   = ksumF[b*128 + o + lk*4 + r];
    }
  }
  __syncthreads();
  // q-GEMM over this wave's 64-n half + in-register denominator + scale
  short4v qpk[2][4];
  #pragma unroll
  for (int ct = 0; ct < 4; ++ct){
    int nr = cg*64 + ct*16 + lr;
    int kn = keyx(nr);
    short8 bfr[4];
    #pragma unroll
    for (int ks = 0; ks < 4; ++ks)
      bfr[ks] = *(const short8*)(S + nr*128 + (((ks*4 + lk) ^ kn) << 3));
    float qv[2][4];
    #pragma unroll
    for (int rtl = 0; rtl < 2; ++rtl){
      floatx4 acc = {0.f,0.f,0.f,0.f};
      #pragma unroll
      for (int ks = 0; ks < 4; ++ks)
        acc = __builtin_amdgcn_mfma_f32_16x16x32_bf16(afr[rtl][ks], bfr[ks], acc, 0,0,0);
      #pragma unroll
      for (int r = 0; r < 4; ++r) qv[rtl][r] = elu1(acc[r] + biasq[rtl][r]);
    }
    float p = 0.f;
    #pragma unroll
    for (int rtl = 0; rtl < 2; ++rtl)
      #pragma unroll
      for (int r = 0; r < 4; ++r) p += ksL[rtl][r] * qv[rtl][r];
    p += __shfl_xor(p, 16);
    p += __shfl_xor(p, 32);                    // sum over lk -> full 32-channel head dot
    float inv = 1.f / (p + 1e-6f);
    #pragma unroll
    for (int rtl = 0; rtl < 2; ++rtl){
      short4v pk;
      #pragma unroll
      for (int r = 0; r < 4; ++r) pk[r] = (short)f2bf(qv[rtl][r] * inv);
      qpk[rtl][ct] = pk;
    }
  }
  // hoist M fragments (wave w -> output rows 16w..16w+16)
  short8 afr2[4];
  #pragma unroll
  for (int ks = 0; ks < 4; ++ks)
    afr2[ks] = *(const short8*)(Mb + ((size_t)b)*16384 + (size_t)(w*16 + lr)*128 + ks*32 + lk*8);
  __syncthreads();                             // all x reads done
  // write q' image [n][c], key n&7
  #pragma unroll
  for (int rtl = 0; rtl < 2; ++rtl){
    int c0 = rg*32 + rtl*16 + lk*4;
    #pragma unroll
    for (int ct = 0; ct < 4; ++ct){
      int n = cg*64 + ct*16 + lr;
      *(short4v*)(S + n*128 + ((((c0 >> 3) ^ (n & 7)) << 3) + (c0 & 7))) = qpk[rtl][ct];
    }
  }
  __syncthreads();
  // Swapped M-GEMM: D[n][c_out]; lane holds c_out = w*16+lr, n-quad = ct*16+lk*4
  unsigned short* hdst = hbT + ((size_t)blk)*16384;   // [c][128 n] tile
  float s1 = 0.f, s2v = 0.f;
  #pragma unroll
  for (int ct = 0; ct < 8; ++ct){
    int nr = ct*16 + lr;
    short8 bfr[4];
    #pragma unroll
    for (int ks = 0; ks < 4; ++ks)
      bfr[ks] = *(const short8*)(S + nr*128 + (((ks*4 + lk) ^ (nr & 7)) << 3));
    floatx4 acc = {0.f,0.f,0.f,0.f};
    #pragma unroll
    for (int ks = 0; ks < 4; ++ks)
      acc = __builtin_amdgcn_mfma_f32_16x16x32_bf16(bfr[ks], afr2[ks], acc, 0,0,0);
    short4v pk;
    #pragma unroll
    for (int r = 0; r < 4; ++r){
      float hv = acc[r];
      pk[r] = (short)f2bf(hv);
      s1 += hv; s2v += hv*hv;
    }
    *(short4v*)(hdst + (w*16 + lr)*128 + ct*16 + lk*4) = pk;
  }
  s1  += __shfl_xor(s1, 16);  s1  += __shfl_xor(s1, 32);
  s2v += __shfl_xor(s2v, 16); s2v += __shfl_xor(s2v, 32);
  if (lane < 16){                              // lk==0 lanes hold channel totals
    int c = w*16 + lr;
    gn2part[((size_t)blk*128 + c)*2 + 0] = s1;
    gn2part[((size_t)blk*128 + c)*2 + 1] = s2v;
  }
}

// ---- K5: GN2 stats (128 t128-tiles per b) ----
__global__ __launch_bounds__(64) void k_gn2stats(const float* __restrict__ gn2part,
    float* __restrict__ mean, float* __restrict__ rstd){
  int b = blockIdx.x >> 5, g = blockIdx.x & 31;
  int lane = threadIdx.x;
  float s = 0.f, s2 = 0.f;
  #pragma unroll
  for (int rr = 0; rr < 2; ++rr){
    int row = lane + rr*64;                    // t128
    const float* p = gn2part + ((size_t)(b*128 + row))*256 + g*8;
    #pragma unroll
    for (int j = 0; j < 4; ++j){ s += p[j*2]; s2 += p[j*2 + 1]; }
  }
  #pragma unroll
  for (int o = 32; o; o >>= 1){ s += __shfl_down(s, o); s2 += __shfl_down(s2, o); }
  if (lane == 0){
    float m = s * (1.f/65536.f);
    float var = s2 * (1.f/65536.f) - m*m;
    mean[blockIdx.x] = m; rstd[blockIdx.x] = rsqrtf(var + 1e-5f);
  }
}

// ---- K6: out = GN2(h) + x  (h: direct vectorized global reads from [c][n] hbT;
//          x: XS staging with 16B-slot rotation (slot+(n>>3))&15 -> ~2-way banks) ----
__global__ __launch_bounds__(256) void k_final(const unsigned short* __restrict__ hbT,
    const unsigned short* __restrict__ xT, float* __restrict__ out,
    const float* __restrict__ mean, const float* __restrict__ rstd,
    const float* __restrict__ g2w, const float* __restrict__ g2b){
  int blk = blockIdx.x;                        // b*128 + t128
  int b = blk >> 7, t128 = blk & 127;
  __shared__ unsigned short XS[16384];
  int t = threadIdx.x;
  const unsigned short* xsrc = xT + ((size_t)(b*64 + (t128 >> 1)))*32768 + (t128 & 1)*16384;
  for (int it = 0; it < 8; ++it){
    int slot = t + it*256;                     // 16B-slot id: n = slot>>4, sl = slot&15
    int n = slot >> 4, sl = slot & 15;
    *(short8*)(XS + n*128 + (((sl + (n >> 3)) & 15) << 3)) = *(const short8*)(xsrc + slot*8);
  }
  __syncthreads();
  const unsigned short* hsrc = hbT + (size_t)blk*16384;
  for (int it = 0; it < 8; ++it){
    int idx = t + it*256;                      // 2048 = 128 c x 16 octets
    int c = idx >> 4, oct = idx & 15;
    int bg = b*32 + (c >> 2);
    float m = mean[bg], r = rstd[bg];
    float sc = r * g2w[c], sh = g2b[c] - m * sc;
    short8 hv = *(const short8*)(hsrc + c*128 + oct*8);   // coalesced 16B global read
    float ov[8];
    #pragma unroll
    for (int j = 0; j < 8; ++j){
      int n = oct*8 + j;
      int sl = (c >> 3) ^ keyx(n);
      unsigned short xv = XS[n*128 + ((((sl + (n >> 3)) & 15) << 3) + (c & 7))];
      ov[j] = bf2f((unsigned short)hv[j])*sc + sh + bf2f(xv);
    }
    float* op = out + ((size_t)(b*128 + c))*HW_ + t128*128 + oct*8;
    float4 o0, o1;
    o0.x = ov[0]; o0.y = ov[1]; o0.z = ov[2]; o0.w = ov[3];
    o1.x = ov[4]; o1.y = ov[5]; o1.z = ov[6]; o1.w = ov[7];
    *(float4*)op = o0; *(float4*)(op + 4) = o1;
  }
}

extern "C" void kernel_launch(void* const* d_in, const int* in_sizes, int n_in,
                              void* d_out, int out_size, void* d_ws, size_t ws_size,
                              hipStream_t stream){
  const float* x    = (const float*)d_in[0];
  const float* g1w  = (const float*)d_in[1];
  const float* g1b  = (const float*)d_in[2];
  const float* wqkv = (const float*)d_in[3];
  const float* wout = (const float*)d_in[4];
  const float* g2w  = (const float*)d_in[5];
  const float* g2b  = (const float*)d_in[6];
  char* ws = (char*)d_ws;
  (void)in_sizes; (void)n_in; (void)out_size; (void)ws_size;

  float* gn1part  = (float*)(ws + 0);                        // 256KB
  float* gn1_mean = (float*)(ws + 262144);
  float* gn1_rstd = (float*)(ws + 264192);
  float* gn2_mean = (float*)(ws + 266240);
  float* gn2_rstd = (float*)(ws + 268288);
  float* bias     = (float*)(ws + 270336);                   // 24KB -> 294912
  unsigned short* woutb = (unsigned short*)(ws + 294912);    // 32KB -> 327680
  float* ksumF    = (float*)(ws + 327680);                   // 8KB  -> 335872
  unsigned short* Mb = (unsigned short*)(ws + 335872);       // 512KB -> 860160
  unsigned short* wqp = (unsigned short*)(ws + 860160);      // 1.5MB -> 2433024
  float* ksumpart = (float*)(ws + 2433024);                  // 512KB -> 2957312
  float* kvpart   = (float*)(ws + 4194304);                  // 16MB -> 20971520
  float* gn2part  = (float*)(ws + 37748736);                 // 2MB -> 39845888
  unsigned short* xT  = (unsigned short*)(ws + 46137344);    // 64MB -> 113246208
  unsigned short* hbT = (unsigned short*)(ws + 113246208);   // 64MB -> 180355072

  k_xprep<<<dim3(1024), dim3(512), 0, stream>>>(x, xT, gn1part);
  k_gn1fin<<<dim3(512), dim3(64), 0, stream>>>(gn1part, gn1_mean, gn1_rstd);
  k_fold<<<dim3(1568), dim3(256), 0, stream>>>(wqkv, wout, g1w, g1b, gn1_mean, gn1_rstd, wqp, bias, woutb);
  k_kv<<<dim3(1024), dim3(512), 0, stream>>>(xT, wqp, bias, kvpart, ksumpart);
  k_kvmfold<<<dim3(64), dim3(256), 0, stream>>>(kvpart, ksumpart, woutb, Mb, ksumF);
  k_attn2<<<dim3(2048), dim3(512), 0, stream>>>(xT, wqp, bias, ksumF, Mb, hbT, gn2part);
  k_gn2stats<<<dim3(512), dim3(64), 0, stream>>>(gn2part, gn2_mean, gn2_rstd);
  k_final<<<dim3(2048), dim3(256), 0, stream>>>(hbT, xT, (float*)d_out, gn2_mean, gn2_rstd, g2w, g2b);
}